// Round 1
// baseline (23488.199 us; speedup 1.0000x reference)
//
#include <hip/hip_runtime.h>
#include <cstdint>
#include <cstddef>

// ---------------------------------------------------------------------------
// LSTM  B=64, T=1024, D=H=512.
// Strategy:
//   * xcvt: x_seq fp32 -> fp16 copy in ws (one-time, ~35us).
//   * lstm_rec: persistent kernel, 256 WGs = 8 batch-groups x 32 column-groups.
//       - WG (g,c): batch rows g*8..g*8+7, hidden units c*16..c*16+15
//         (=> 64 gate columns: [f|i|g|o] x 16).
//       - Wh slice (64x512) and Wx slice (64x512) held in LDS as fp16 for the
//         whole sequence (133 KB LDS -> 1 WG/CU).
//       - Per step: gates = x@Wx^T (shadow-computed last step, off critical
//         path) + h@Wh^T (MFMA 16x16x32 f16, fp32 accum), sigmoid/tanh,
//         c in registers, h published fp16 to a per-group global buffer.
//       - Sync: per-WG flag cacheline, store-release / acquire-poll among the
//         32 WGs of a group only. blockIdx = c*8+g keeps a group on one XCD
//         (perf heuristic only; agent-scope ops keep it correct anywhere).
// ---------------------------------------------------------------------------

typedef _Float16 half8  __attribute__((ext_vector_type(8)));
typedef _Float16 half4v __attribute__((ext_vector_type(4)));
typedef float    float4v __attribute__((ext_vector_type(4)));

__device__ __forceinline__ float sigm(float x) { return 1.f / (1.f + __expf(-x)); }
__device__ __forceinline__ float tanh_f(float x) { return 2.f / (1.f + __expf(-2.f * x)) - 1.f; }

// ----------------------------- x fp32 -> fp16 ------------------------------
__global__ __launch_bounds__(256) void xcvt(const float* __restrict__ X,
                                            _Float16* __restrict__ XH) {
    size_t i = ((size_t)blockIdx.x * 256 + threadIdx.x) * 8;
    float4 a = *(const float4*)(X + i);
    float4 b = *(const float4*)(X + i + 4);
    half8 v;
    v[0] = (_Float16)a.x; v[1] = (_Float16)a.y; v[2] = (_Float16)a.z; v[3] = (_Float16)a.w;
    v[4] = (_Float16)b.x; v[5] = (_Float16)b.y; v[6] = (_Float16)b.z; v[7] = (_Float16)b.w;
    *(half8*)(XH + i) = v;
}

// ------------------------------- recurrence --------------------------------
__global__ __launch_bounds__(256, 1) void lstm_rec(
    const float* __restrict__ Whf, const float* __restrict__ Whi,
    const float* __restrict__ Whg, const float* __restrict__ Who,
    const float* __restrict__ Wxf, const float* __restrict__ Wxi,
    const float* __restrict__ Wxg, const float* __restrict__ Wxo,
    const float* __restrict__ bxf, const float* __restrict__ bxi,
    const float* __restrict__ bxg, const float* __restrict__ bxo,
    const float* __restrict__ bhf, const float* __restrict__ bhi,
    const float* __restrict__ bhg, const float* __restrict__ bho,
    const _Float16* __restrict__ XH,   // [64][1024][512] fp16
    unsigned int* __restrict__ flags,  // 256 flags, 128B apart (stride 32 uints)
    _Float16* __restrict__ hws,        // [2][8][8][512] fp16 (zero-initialized)
    float* __restrict__ out)           // [64][512] fp32
{
    const int blk  = blockIdx.x;
    const int g    = blk & 7;    // batch group (XCD under round-robin)
    const int c    = blk >> 3;   // column group 0..31
    const int tid  = threadIdx.x;
    const int w    = tid >> 6;   // wave 0..3 -> gate-col tile w*16..w*16+15
    const int lane = tid & 63;
    const int l15  = lane & 15;
    const int quad = lane >> 4;
    const int m    = l15 & 7;    // batch row within group (rows 8..15 dup rows 0..7)

    __shared__ _Float16 Wls[64][520];  // Wh slice, rows = [f16|i16|g16|o16]
    __shared__ _Float16 Xls[64][520];  // Wx slice, same layout
    __shared__ float    gs[8][65];     // gate preacts [row][gatecol]

    // ---- one-time: weight slices -> LDS fp16 ----
    const float* WhSeg[4] = {Whf, Whi, Whg, Who};
    const float* WxSeg[4] = {Wxf, Wxi, Wxg, Wxo};
    for (int e = tid * 4; e < 64 * 512; e += 1024) {
        int row = e >> 9, col = e & 511;
        int seg = row >> 4;
        int srow = c * 16 + (row & 15);
        float4 vh = *(const float4*)(WhSeg[seg] + (size_t)srow * 512 + col);
        float4 vx = *(const float4*)(WxSeg[seg] + (size_t)srow * 512 + col);
        half4v th = {(_Float16)vh.x, (_Float16)vh.y, (_Float16)vh.z, (_Float16)vh.w};
        half4v tx = {(_Float16)vx.x, (_Float16)vx.y, (_Float16)vx.z, (_Float16)vx.w};
        *(half4v*)&Wls[row][col] = th;
        *(half4v*)&Xls[row][col] = tx;
    }
    __syncthreads();

    // ---- elementwise role setup (tid<128: 8 rows x 16 units) ----
    const int erow = tid >> 4;
    const int eu   = tid & 15;
    float bsf = 0.f, bsi = 0.f, bsg = 0.f, bso = 0.f;
    if (tid < 128) {
        int u = c * 16 + eu;
        bsf = bxf[u] + bhf[u];
        bsi = bxi[u] + bhi[u];
        bsg = bxg[u] + bhg[u];
        bso = bxo[u] + bho[u];
    }
    float cstate = 0.f;

    unsigned int* myflag   = flags + (size_t)(g * 32 + c) * 32;
    unsigned int* pollflag = flags + (size_t)(g * 32 + (lane & 31)) * 32;
    unsigned int lastv = 0;

    // ---- x-projection shadow pipeline: acc_x for step 0 ----
    const size_t xrow = (size_t)(g * 8 + m) * 1024 * 512 + (size_t)quad * 8;
    half8 xf[16];
#pragma unroll
    for (int kk = 0; kk < 16; kk++) xf[kk] = *(const half8*)(XH + xrow + kk * 32);
    float4v accx = {0.f, 0.f, 0.f, 0.f};
#pragma unroll
    for (int kk = 0; kk < 16; kk++) {
        half8 b = *(const half8*)&Xls[w * 16 + l15][kk * 32 + quad * 8];
        accx = __builtin_amdgcn_mfma_f32_16x16x32_f16(xf[kk], b, accx, 0, 0, 0);
    }

    for (int t = 0; t < 1024; t++) {
        // ---- wait: all peers in this group finished step t-1 ----
        if (w == 0) {
            while (!__all((int)(lastv >= (unsigned)t))) {
                lastv = __hip_atomic_load(pollflag, __ATOMIC_ACQUIRE, __HIP_MEMORY_SCOPE_AGENT);
            }
        }
        __syncthreads();

        // ---- h-GEMM: acc = acc_x + h_{t} @ Wh_slice^T (2 accum chains) ----
        const _Float16* hsrc = hws + (size_t)(t & 1) * 32768 + g * 4096
                             + (size_t)m * 512 + quad * 8;
        half8 hf[16];
#pragma unroll
        for (int kk = 0; kk < 16; kk++) hf[kk] = *(const half8*)(hsrc + kk * 32);
        float4v acca = accx;
        float4v accb = {0.f, 0.f, 0.f, 0.f};
#pragma unroll
        for (int kk = 0; kk < 16; kk += 2) {
            half8 b0 = *(const half8*)&Wls[w * 16 + l15][kk * 32 + quad * 8];
            half8 b1 = *(const half8*)&Wls[w * 16 + l15][(kk + 1) * 32 + quad * 8];
            acca = __builtin_amdgcn_mfma_f32_16x16x32_f16(hf[kk], b0, acca, 0, 0, 0);
            accb = __builtin_amdgcn_mfma_f32_16x16x32_f16(hf[kk + 1], b1, accb, 0, 0, 0);
        }

        // ---- gate preacts -> LDS (real rows 0..7 live in quads 0,1) ----
        if (quad < 2) {
#pragma unroll
            for (int r = 0; r < 4; r++)
                gs[quad * 4 + r][w * 16 + l15] = acca[r] + accb[r];
        }
        __syncthreads();

        // ---- elementwise LSTM cell update ----
        if (tid < 128) {
            float pf = gs[erow][eu]      + bsf;
            float pi = gs[erow][eu + 16] + bsi;
            float pg = gs[erow][eu + 32] + bsg;
            float po = gs[erow][eu + 48] + bso;
            float fg = sigm(pf), ig = sigm(pi), gg = tanh_f(pg), og = sigm(po);
            cstate = fg * cstate + ig * gg;
            float hn = og * tanh_f(cstate);
            hws[(size_t)((t + 1) & 1) * 32768 + g * 4096
                + (size_t)erow * 512 + c * 16 + eu] = (_Float16)hn;
            if (t == 1023)
                out[(size_t)(g * 8 + erow) * 512 + c * 16 + eu] = hn;
        }

        // ---- publish: fence, then release own flag ----
        __threadfence();
        __syncthreads();
        if (tid == 0)
            __hip_atomic_store(myflag, (unsigned)(t + 1), __ATOMIC_RELEASE,
                               __HIP_MEMORY_SCOPE_AGENT);

        // ---- shadow work for step t+1 (off critical path): x-GEMM ----
        int tn = (t < 1023) ? (t + 1) : 0;
        const _Float16* xp = XH + xrow + (size_t)tn * 512;
#pragma unroll
        for (int kk = 0; kk < 16; kk++) xf[kk] = *(const half8*)(xp + kk * 32);
        float4v ax = {0.f, 0.f, 0.f, 0.f};
#pragma unroll
        for (int kk = 0; kk < 16; kk++) {
            half8 b = *(const half8*)&Xls[w * 16 + l15][kk * 32 + quad * 8];
            ax = __builtin_amdgcn_mfma_f32_16x16x32_f16(xf[kk], b, ax, 0, 0, 0);
        }
        accx = ax;
    }
}

// ------------------------------- launcher ----------------------------------
extern "C" void kernel_launch(void* const* d_in, const int* in_sizes, int n_in,
                              void* d_out, int out_size, void* d_ws, size_t ws_size,
                              hipStream_t stream) {
    const float* X   = (const float*)d_in[0];
    const float* Whf = (const float*)d_in[1];  const float* bhf = (const float*)d_in[2];
    const float* Wxf = (const float*)d_in[3];  const float* bxf = (const float*)d_in[4];
    const float* Whi = (const float*)d_in[5];  const float* bhi = (const float*)d_in[6];
    const float* Wxi = (const float*)d_in[7];  const float* bxi = (const float*)d_in[8];
    const float* Whg = (const float*)d_in[9];  const float* bhg = (const float*)d_in[10];
    const float* Wxg = (const float*)d_in[11]; const float* bxg = (const float*)d_in[12];
    const float* Who = (const float*)d_in[13]; const float* bho = (const float*)d_in[14];
    const float* Wxo = (const float*)d_in[15]; const float* bxo = (const float*)d_in[16];

    // ws layout: [0,32KB) flags | [32KB,192KB) h double buffer | [1MB,65MB) XH
    const size_t need = (1u << 20) + (size_t)64 * 1024 * 512 * 2 * sizeof(_Float16) / 2
                        ; // 1MB + 64MB
    if (ws_size < (size_t)68157440) return;  // insufficient workspace: bail visibly

    char* ws = (char*)d_ws;
    unsigned int* flags = (unsigned int*)ws;
    _Float16* hws = (_Float16*)(ws + 32768);
    _Float16* XH  = (_Float16*)(ws + (1 << 20));
    (void)need; (void)in_sizes; (void)n_in; (void)out_size;

    hipMemsetAsync(d_ws, 0, 1 << 20, stream);
    xcvt<<<16384, 256, 0, stream>>>(X, XH);
    lstm_rec<<<256, 256, 0, stream>>>(Whf, Whi, Whg, Who, Wxf, Wxi, Wxg, Wxo,
                                      bxf, bxi, bxg, bxo, bhf, bhi, bhg, bho,
                                      XH, flags, hws, (float*)d_out);
}

// Round 2
// 6618.398 us; speedup vs baseline: 3.5489x; 3.5489x over previous
//
#include <hip/hip_runtime.h>
#include <cstdint>
#include <cstddef>

// ---------------------------------------------------------------------------
// LSTM  B=64, T=1024, D=H=512.
//   * xcvt: x_seq fp32 -> fp16 in ws (one-time, ~35us).
//   * lstm_rec: persistent, 256 WGs = 8 batch-groups x 32 column-groups.
//     WG (g,c): batch rows g*8..g*8+7, hidden units c*16..c*16+15.
//     Wh & Wx slices LDS-resident fp16 (133 KB, 1 WG/CU).
//     Cross-WG handoff: RELAXED agent-scope atomics only (global_* sc1,
//     device-coherent, NO buffer_inv/buffer_wbl2 cache walks — R1 showed
//     acquire/release fences cost ~23us/step). Ordering by explicit
//     s_waitcnt vmcnt(0) between h stores and flag store (same wave).
//     x-projection shadow-computed one step ahead, off the critical path.
// ---------------------------------------------------------------------------

typedef _Float16 half8  __attribute__((ext_vector_type(8)));
typedef _Float16 half4v __attribute__((ext_vector_type(4)));
typedef float    float4v __attribute__((ext_vector_type(4)));

__device__ __forceinline__ float sigm(float x) { return 1.f / (1.f + __expf(-x)); }
__device__ __forceinline__ float tanh_f(float x) { return 2.f / (1.f + __expf(-2.f * x)) - 1.f; }

// ----------------------------- x fp32 -> fp16 ------------------------------
__global__ __launch_bounds__(256) void xcvt(const float* __restrict__ X,
                                            _Float16* __restrict__ XH) {
    size_t i = ((size_t)blockIdx.x * 256 + threadIdx.x) * 8;
    float4 a = *(const float4*)(X + i);
    float4 b = *(const float4*)(X + i + 4);
    half8 v;
    v[0] = (_Float16)a.x; v[1] = (_Float16)a.y; v[2] = (_Float16)a.z; v[3] = (_Float16)a.w;
    v[4] = (_Float16)b.x; v[5] = (_Float16)b.y; v[6] = (_Float16)b.z; v[7] = (_Float16)b.w;
    *(half8*)(XH + i) = v;
}

// ------------------------------- recurrence --------------------------------
__global__ __launch_bounds__(256, 1) void lstm_rec(
    const float* __restrict__ Whf, const float* __restrict__ Whi,
    const float* __restrict__ Whg, const float* __restrict__ Who,
    const float* __restrict__ Wxf, const float* __restrict__ Wxi,
    const float* __restrict__ Wxg, const float* __restrict__ Wxo,
    const float* __restrict__ bxf, const float* __restrict__ bxi,
    const float* __restrict__ bxg, const float* __restrict__ bxo,
    const float* __restrict__ bhf, const float* __restrict__ bhi,
    const float* __restrict__ bhg, const float* __restrict__ bho,
    const _Float16* __restrict__ XH,   // [64][1024][512] fp16
    unsigned int* __restrict__ flags,  // 256 flags, 128B apart (stride 32 uints)
    unsigned int* __restrict__ hws,    // [2][8][8][256] u32 (=2 fp16 each), zeroed
    float* __restrict__ out)           // [64][512] fp32
{
    const int blk  = blockIdx.x;
    const int g    = blk & 7;    // batch group (one XCD under round-robin)
    const int c    = blk >> 3;   // column group 0..31
    const int tid  = threadIdx.x;
    const int w    = tid >> 6;   // wave 0..3 -> gate-col tile w*16..w*16+15
    const int lane = tid & 63;
    const int l15  = lane & 15;
    const int quad = lane >> 4;
    const int m    = l15 & 7;    // batch row within group (rows 8..15 dup 0..7)

    __shared__ _Float16 Wls[64][520];  // Wh slice, rows = [f16|i16|g16|o16]
    __shared__ _Float16 Xls[64][520];  // Wx slice, same layout
    __shared__ float    gs[8][65];     // gate preacts [row][gatecol]

    // ---- one-time: weight slices -> LDS fp16 ----
    const float* WhSeg[4] = {Whf, Whi, Whg, Who};
    const float* WxSeg[4] = {Wxf, Wxi, Wxg, Wxo};
    for (int e = tid * 4; e < 64 * 512; e += 1024) {
        int row = e >> 9, col = e & 511;
        int seg = row >> 4;
        int srow = c * 16 + (row & 15);
        float4 vh = *(const float4*)(WhSeg[seg] + (size_t)srow * 512 + col);
        float4 vx = *(const float4*)(WxSeg[seg] + (size_t)srow * 512 + col);
        half4v th = {(_Float16)vh.x, (_Float16)vh.y, (_Float16)vh.z, (_Float16)vh.w};
        half4v tx = {(_Float16)vx.x, (_Float16)vx.y, (_Float16)vx.z, (_Float16)vx.w};
        *(half4v*)&Wls[row][col] = th;
        *(half4v*)&Xls[row][col] = tx;
    }
    __syncthreads();

    // ---- elementwise role: wave 0 only, 64 threads x (1 row, 2 units) ----
    const int erow = tid >> 3;        // 0..7  (valid for tid<64)
    const int ep   = tid & 7;         // unit pair 0..7 -> units 2ep, 2ep+1
    float bs[8] = {0.f};              // f0,i0,g0,o0,f1,i1,g1,o1
    if (tid < 64) {
        int u0 = c * 16 + 2 * ep, u1 = u0 + 1;
        bs[0] = bxf[u0] + bhf[u0];  bs[4] = bxf[u1] + bhf[u1];
        bs[1] = bxi[u0] + bhi[u0];  bs[5] = bxi[u1] + bhi[u1];
        bs[2] = bxg[u0] + bhg[u0];  bs[6] = bxg[u1] + bhg[u1];
        bs[3] = bxo[u0] + bho[u0];  bs[7] = bxo[u1] + bho[u1];
    }
    float c0s = 0.f, c1s = 0.f;

    unsigned int* myflag   = flags + (size_t)(g * 32 + c) * 32;
    unsigned int* pollflag = flags + (size_t)(g * 32 + (lane & 31)) * 32;
    unsigned int lastv = 0;

    // ---- x-projection shadow: acc_x for step 0 ----
    const size_t xrow = (size_t)(g * 8 + m) * 1024 * 512 + (size_t)quad * 8;
    half8 xf[16];
#pragma unroll
    for (int kk = 0; kk < 16; kk++) xf[kk] = *(const half8*)(XH + xrow + kk * 32);
    float4v accx = {0.f, 0.f, 0.f, 0.f};
#pragma unroll
    for (int kk = 0; kk < 16; kk++) {
        half8 b = *(const half8*)&Xls[w * 16 + l15][kk * 32 + quad * 8];
        accx = __builtin_amdgcn_mfma_f32_16x16x32_f16(xf[kk], b, accx, 0, 0, 0);
    }

    for (int t = 0; t < 1024; t++) {
        // ---- wait: all peers in this group finished step t-1 (relaxed) ----
        if (w == 0) {
            while (!__all((int)(lastv >= (unsigned)t))) {
                lastv = __hip_atomic_load(pollflag, __ATOMIC_RELAXED,
                                          __HIP_MEMORY_SCOPE_AGENT);
            }
        }
        __syncthreads();
        asm volatile("" ::: "memory");

        // ---- load h_t fragments (relaxed agent 8B loads, sc1: no stale) ----
        const unsigned long long* hsrc64 = (const unsigned long long*)hws
            + (size_t)(t & 1) * 8192 + g * 1024 + (size_t)m * 128 + quad * 2;
        half8 hf[16];
#pragma unroll
        for (int kk = 0; kk < 16; kk++) {
            unsigned long long lo = __hip_atomic_load(hsrc64 + kk * 8,
                __ATOMIC_RELAXED, __HIP_MEMORY_SCOPE_AGENT);
            unsigned long long hi = __hip_atomic_load(hsrc64 + kk * 8 + 1,
                __ATOMIC_RELAXED, __HIP_MEMORY_SCOPE_AGENT);
            union { unsigned long long q[2]; half8 v; } u;
            u.q[0] = lo; u.q[1] = hi;
            hf[kk] = u.v;
        }

        // ---- h-GEMM: acc = acc_x + h_t @ Wh_slice^T ----
        float4v acca = accx;
        float4v accb = {0.f, 0.f, 0.f, 0.f};
#pragma unroll
        for (int kk = 0; kk < 16; kk += 2) {
            half8 b0 = *(const half8*)&Wls[w * 16 + l15][kk * 32 + quad * 8];
            half8 b1 = *(const half8*)&Wls[w * 16 + l15][(kk + 1) * 32 + quad * 8];
            acca = __builtin_amdgcn_mfma_f32_16x16x32_f16(hf[kk], b0, acca, 0, 0, 0);
            accb = __builtin_amdgcn_mfma_f32_16x16x32_f16(hf[kk + 1], b1, accb, 0, 0, 0);
        }

        // ---- gate preacts -> LDS (rows 0..7 live in quads 0,1) ----
        if (quad < 2) {
#pragma unroll
            for (int r = 0; r < 4; r++)
                gs[quad * 4 + r][w * 16 + l15] = acca[r] + accb[r];
        }
        __syncthreads();

        // ---- elementwise LSTM update: wave 0 only, then publish ----
        if (tid < 64) {
            float pf0 = gs[erow][2 * ep]      + bs[0];
            float pi0 = gs[erow][2 * ep + 16] + bs[1];
            float pg0 = gs[erow][2 * ep + 32] + bs[2];
            float po0 = gs[erow][2 * ep + 48] + bs[3];
            float pf1 = gs[erow][2 * ep + 1]  + bs[4];
            float pi1 = gs[erow][2 * ep + 17] + bs[5];
            float pg1 = gs[erow][2 * ep + 33] + bs[6];
            float po1 = gs[erow][2 * ep + 49] + bs[7];
            c0s = sigm(pf0) * c0s + sigm(pi0) * tanh_f(pg0);
            c1s = sigm(pf1) * c1s + sigm(pi1) * tanh_f(pg1);
            float hn0 = sigm(po0) * tanh_f(c0s);
            float hn1 = sigm(po1) * tanh_f(c1s);
            union { _Float16 h[2]; unsigned int u; } pk;
            pk.h[0] = (_Float16)hn0; pk.h[1] = (_Float16)hn1;
            unsigned int* hd = hws + (size_t)((t + 1) & 1) * 16384 + g * 2048
                             + (size_t)erow * 256 + c * 8 + ep;
            __hip_atomic_store(hd, pk.u, __ATOMIC_RELAXED,
                               __HIP_MEMORY_SCOPE_AGENT);
            if (t == 1023) {
                size_t ob = (size_t)(g * 8 + erow) * 512 + c * 16 + 2 * ep;
                out[ob]     = hn0;
                out[ob + 1] = hn1;
            }
            // drain own wave's h stores to the coherence point, then flag
            asm volatile("s_waitcnt vmcnt(0)" ::: "memory");
            if (tid == 0)
                __hip_atomic_store(myflag, (unsigned)(t + 1), __ATOMIC_RELAXED,
                                   __HIP_MEMORY_SCOPE_AGENT);
        }

        // ---- shadow x-GEMM for step t+1 (off critical path) ----
        int tn = (t < 1023) ? (t + 1) : 0;
        const _Float16* xp = XH + xrow + (size_t)tn * 512;
#pragma unroll
        for (int kk = 0; kk < 16; kk++) xf[kk] = *(const half8*)(xp + kk * 32);
        float4v ax = {0.f, 0.f, 0.f, 0.f};
#pragma unroll
        for (int kk = 0; kk < 16; kk++) {
            half8 b = *(const half8*)&Xls[w * 16 + l15][kk * 32 + quad * 8];
            ax = __builtin_amdgcn_mfma_f32_16x16x32_f16(xf[kk], b, ax, 0, 0, 0);
        }
        accx = ax;
    }
}

// ------------------------------- launcher ----------------------------------
extern "C" void kernel_launch(void* const* d_in, const int* in_sizes, int n_in,
                              void* d_out, int out_size, void* d_ws, size_t ws_size,
                              hipStream_t stream) {
    const float* X   = (const float*)d_in[0];
    const float* Whf = (const float*)d_in[1];  const float* bhf = (const float*)d_in[2];
    const float* Wxf = (const float*)d_in[3];  const float* bxf = (const float*)d_in[4];
    const float* Whi = (const float*)d_in[5];  const float* bhi = (const float*)d_in[6];
    const float* Wxi = (const float*)d_in[7];  const float* bxi = (const float*)d_in[8];
    const float* Whg = (const float*)d_in[9];  const float* bhg = (const float*)d_in[10];
    const float* Wxg = (const float*)d_in[11]; const float* bxg = (const float*)d_in[12];
    const float* Who = (const float*)d_in[13]; const float* bho = (const float*)d_in[14];
    const float* Wxo = (const float*)d_in[15]; const float* bxo = (const float*)d_in[16];

    // ws layout: [0,32KB) flags | [32KB,160KB) h double buffer | [1MB,65MB) XH
    if (ws_size < (size_t)68157440) return;  // need 65 MiB

    char* ws = (char*)d_ws;
    unsigned int* flags = (unsigned int*)ws;
    unsigned int* hws   = (unsigned int*)(ws + 32768);
    _Float16*     XH    = (_Float16*)(ws + (1 << 20));
    (void)in_sizes; (void)n_in; (void)out_size;

    hipMemsetAsync(d_ws, 0, 1 << 20, stream);
    xcvt<<<16384, 256, 0, stream>>>(X, XH);
    lstm_rec<<<256, 256, 0, stream>>>(Whf, Whi, Whg, Who, Wxf, Wxi, Wxg, Wxo,
                                      bxf, bxi, bxg, bxo, bhf, bhi, bhg, bho,
                                      XH, flags, hws, (float*)d_out);
}

// Round 3
// 4018.845 us; speedup vs baseline: 5.8445x; 1.6468x over previous
//
#include <hip/hip_runtime.h>
#include <cstdint>
#include <cstddef>

// ---------------------------------------------------------------------------
// LSTM  B=64, T=1024, D=H=512.
//   * xcvt: x_seq fp32 -> fp16 in ws (one-time).
//   * lstm_rec: persistent, 256 WGs = 8 batch-groups x 32 column-groups.
//     WG (g,c): batch rows g*8..g*8+7, hidden units c*16..c*16+15.
//     Wh & Wx slices LDS-resident fp16 (133 KB, 1 WG/CU).
//     R3: SELF-SYNCHRONIZING TAGGED h — each h element is a u32
//     (step_tag<<16 | fp16). Producer publishes fire-and-forget (no vmcnt
//     ack, no flags). Consumer's poll IS the data load: whole WG
//     cooperatively spin-loads the group's tagged h once (per-lane spin,
//     64B/lane), stages payload into LDS, all waves read A-fragments from
//     LDS. Collapses ~4 serial L3 round trips/step to ~1.5 and cuts L3
//     h-read traffic 8x. Double-buffer + monotone tags make overwrite safe:
//     a WG writes tag t+1 only after observing ALL tags t, which implies
//     every peer finished reading tags t-1 from that buffer.
// ---------------------------------------------------------------------------

typedef _Float16 half8  __attribute__((ext_vector_type(8)));
typedef _Float16 half4v __attribute__((ext_vector_type(4)));
typedef float    float4v __attribute__((ext_vector_type(4)));

__device__ __forceinline__ float sigm(float x) { return 1.f / (1.f + __expf(-x)); }
__device__ __forceinline__ float tanh_f(float x) { return 2.f / (1.f + __expf(-2.f * x)) - 1.f; }

// ----------------------------- x fp32 -> fp16 ------------------------------
__global__ __launch_bounds__(256) void xcvt(const float* __restrict__ X,
                                            _Float16* __restrict__ XH) {
    size_t i = ((size_t)blockIdx.x * 256 + threadIdx.x) * 8;
    float4 a = *(const float4*)(X + i);
    float4 b = *(const float4*)(X + i + 4);
    half8 v;
    v[0] = (_Float16)a.x; v[1] = (_Float16)a.y; v[2] = (_Float16)a.z; v[3] = (_Float16)a.w;
    v[4] = (_Float16)b.x; v[5] = (_Float16)b.y; v[6] = (_Float16)b.z; v[7] = (_Float16)b.w;
    *(half8*)(XH + i) = v;
}

// ------------------------------- recurrence --------------------------------
__global__ __launch_bounds__(256, 1) void lstm_rec(
    const float* __restrict__ Whf, const float* __restrict__ Whi,
    const float* __restrict__ Whg, const float* __restrict__ Who,
    const float* __restrict__ Wxf, const float* __restrict__ Wxi,
    const float* __restrict__ Wxg, const float* __restrict__ Wxo,
    const float* __restrict__ bxf, const float* __restrict__ bxi,
    const float* __restrict__ bxg, const float* __restrict__ bxo,
    const float* __restrict__ bhf, const float* __restrict__ bhi,
    const float* __restrict__ bhg, const float* __restrict__ bho,
    const _Float16* __restrict__ XH,        // [64][1024][512] fp16
    unsigned long long* __restrict__ hws,   // tagged h [2][8][8][256] u64, zeroed
    float* __restrict__ out)                // [64][512] fp32
{
    const int blk  = blockIdx.x;
    const int g    = blk & 7;    // batch group (one XCD under round-robin)
    const int c    = blk >> 3;   // column group 0..31
    const int tid  = threadIdx.x;
    const int w    = tid >> 6;   // wave 0..3 -> gate-col tile w*16..w*16+15
    const int lane = tid & 63;
    const int l15  = lane & 15;
    const int quad = lane >> 4;
    const int m    = l15 & 7;    // batch row within group (rows 8..15 dup 0..7)

    __shared__ _Float16 Wls[64][520];  // Wh slice, rows = [f16|i16|g16|o16]
    __shared__ _Float16 Xls[64][520];  // Wx slice, same layout
    __shared__ _Float16 hls[8][520];   // staged h_t payload [row][512 units]
    __shared__ float    gs[8][65];     // gate preacts [row][gatecol]

    // ---- one-time: weight slices -> LDS fp16 ----
    const float* WhSeg[4] = {Whf, Whi, Whg, Who};
    const float* WxSeg[4] = {Wxf, Wxi, Wxg, Wxo};
    for (int e = tid * 4; e < 64 * 512; e += 1024) {
        int row = e >> 9, col = e & 511;
        int seg = row >> 4;
        int srow = c * 16 + (row & 15);
        float4 vh = *(const float4*)(WhSeg[seg] + (size_t)srow * 512 + col);
        float4 vx = *(const float4*)(WxSeg[seg] + (size_t)srow * 512 + col);
        half4v th = {(_Float16)vh.x, (_Float16)vh.y, (_Float16)vh.z, (_Float16)vh.w};
        half4v tx = {(_Float16)vx.x, (_Float16)vx.y, (_Float16)vx.z, (_Float16)vx.w};
        *(half4v*)&Wls[row][col] = th;
        *(half4v*)&Xls[row][col] = tx;
    }
    __syncthreads();

    // ---- elementwise role: wave 0 only, 64 threads x (1 row, 2 units) ----
    const int erow = tid >> 3;        // 0..7  (valid for tid<64)
    const int ep   = tid & 7;         // unit pair 0..7 -> units 2ep, 2ep+1
    float bs[8] = {0.f};              // f0,i0,g0,o0,f1,i1,g1,o1
    if (tid < 64) {
        int u0 = c * 16 + 2 * ep, u1 = u0 + 1;
        bs[0] = bxf[u0] + bhf[u0];  bs[4] = bxf[u1] + bhf[u1];
        bs[1] = bxi[u0] + bhi[u0];  bs[5] = bxi[u1] + bhi[u1];
        bs[2] = bxg[u0] + bhg[u0];  bs[6] = bxg[u1] + bhg[u1];
        bs[3] = bxo[u0] + bho[u0];  bs[7] = bxo[u1] + bho[u1];
    }
    float c0s = 0.f, c1s = 0.f;

    // consumer staging role: lane loads 16 tagged u32 (8 u64) of group h
    const int crow = tid >> 5;          // 0..7
    const int ccol = (tid & 31) << 4;   // 0..496

    // ---- x-projection shadow: acc_x for step 0 ----
    const size_t xrow = (size_t)(g * 8 + m) * 1024 * 512 + (size_t)quad * 8;
    half8 xf[16];
#pragma unroll
    for (int kk = 0; kk < 16; kk++) xf[kk] = *(const half8*)(XH + xrow + kk * 32);
    float4v accx = {0.f, 0.f, 0.f, 0.f};
#pragma unroll
    for (int kk = 0; kk < 16; kk++) {
        half8 b = *(const half8*)&Xls[w * 16 + l15][kk * 32 + quad * 8];
        accx = __builtin_amdgcn_mfma_f32_16x16x32_f16(xf[kk], b, accx, 0, 0, 0);
    }

    for (int t = 0; t < 1024; t++) {
        // ---- cooperative tagged spin-load of h_t -> LDS (poll IS the load)
        {
            const unsigned long long* hsrc = hws + (size_t)(t & 1) * 16384
                                           + (size_t)g * 2048 + (size_t)tid * 8;
            const unsigned long long T =
                ((unsigned long long)(unsigned)t << 16) |
                ((unsigned long long)(unsigned)t << 48);
            unsigned long long q[8];
            for (;;) {
                unsigned long long bad = 0;
#pragma unroll
                for (int j = 0; j < 8; j++)
                    q[j] = __hip_atomic_load(hsrc + j, __ATOMIC_RELAXED,
                                             __HIP_MEMORY_SCOPE_AGENT);
#pragma unroll
                for (int j = 0; j < 8; j++)
                    bad |= (q[j] ^ T) & 0xFFFF0000FFFF0000ULL;
                if (!bad) break;
            }
            unsigned int* hd = (unsigned int*)&hls[crow][ccol];
#pragma unroll
            for (int j = 0; j < 8; j++)
                hd[j] = (unsigned int)(q[j] & 0xFFFF) |
                        (((unsigned int)(q[j] >> 32)) << 16);
        }
        __syncthreads();

        // ---- h-GEMM: acc = acc_x + h_t @ Wh_slice^T (A-frags from LDS) ----
        float4v acca = accx;
        float4v accb = {0.f, 0.f, 0.f, 0.f};
#pragma unroll
        for (int kk = 0; kk < 16; kk += 2) {
            half8 a0 = *(const half8*)&hls[m][kk * 32 + quad * 8];
            half8 a1 = *(const half8*)&hls[m][(kk + 1) * 32 + quad * 8];
            half8 b0 = *(const half8*)&Wls[w * 16 + l15][kk * 32 + quad * 8];
            half8 b1 = *(const half8*)&Wls[w * 16 + l15][(kk + 1) * 32 + quad * 8];
            acca = __builtin_amdgcn_mfma_f32_16x16x32_f16(a0, b0, acca, 0, 0, 0);
            accb = __builtin_amdgcn_mfma_f32_16x16x32_f16(a1, b1, accb, 0, 0, 0);
        }

        // ---- gate preacts -> LDS (rows 0..7 live in quads 0,1) ----
        if (quad < 2) {
#pragma unroll
            for (int r = 0; r < 4; r++)
                gs[quad * 4 + r][w * 16 + l15] = acca[r] + accb[r];
        }
        __syncthreads();

        // ---- elementwise LSTM update + tagged publish (wave 0 only) ----
        if (tid < 64) {
            float pf0 = gs[erow][2 * ep]      + bs[0];
            float pi0 = gs[erow][2 * ep + 16] + bs[1];
            float pg0 = gs[erow][2 * ep + 32] + bs[2];
            float po0 = gs[erow][2 * ep + 48] + bs[3];
            float pf1 = gs[erow][2 * ep + 1]  + bs[4];
            float pi1 = gs[erow][2 * ep + 17] + bs[5];
            float pg1 = gs[erow][2 * ep + 33] + bs[6];
            float po1 = gs[erow][2 * ep + 49] + bs[7];
            c0s = sigm(pf0) * c0s + sigm(pi0) * tanh_f(pg0);
            c1s = sigm(pf1) * c1s + sigm(pi1) * tanh_f(pg1);
            float hn0 = sigm(po0) * tanh_f(c0s);
            float hn1 = sigm(po1) * tanh_f(c1s);
            union { _Float16 f; unsigned short u; } cv0, cv1;
            cv0.f = (_Float16)hn0; cv1.f = (_Float16)hn1;
            unsigned int tag = (unsigned)(t + 1) << 16;
            unsigned long long qv = (unsigned long long)(tag | cv0.u)
                                  | ((unsigned long long)(tag | cv1.u) << 32);
            unsigned long long* hd = hws + (size_t)((t + 1) & 1) * 16384
                                   + (size_t)g * 2048 + (size_t)erow * 256
                                   + c * 8 + ep;
            __hip_atomic_store(hd, qv, __ATOMIC_RELAXED,
                               __HIP_MEMORY_SCOPE_AGENT);
            if (t == 1023) {
                size_t ob = (size_t)(g * 8 + erow) * 512 + c * 16 + 2 * ep;
                out[ob]     = hn0;
                out[ob + 1] = hn1;
            }
        }

        // ---- shadow x-GEMM for step t+1 (off critical path) ----
        int tn = (t < 1023) ? (t + 1) : 0;
        const _Float16* xp = XH + xrow + (size_t)tn * 512;
#pragma unroll
        for (int kk = 0; kk < 16; kk++) xf[kk] = *(const half8*)(xp + kk * 32);
        float4v ax = {0.f, 0.f, 0.f, 0.f};
#pragma unroll
        for (int kk = 0; kk < 16; kk++) {
            half8 b = *(const half8*)&Xls[w * 16 + l15][kk * 32 + quad * 8];
            ax = __builtin_amdgcn_mfma_f32_16x16x32_f16(xf[kk], b, ax, 0, 0, 0);
        }
        accx = ax;
    }
}

// ------------------------------- launcher ----------------------------------
extern "C" void kernel_launch(void* const* d_in, const int* in_sizes, int n_in,
                              void* d_out, int out_size, void* d_ws, size_t ws_size,
                              hipStream_t stream) {
    const float* X   = (const float*)d_in[0];
    const float* Whf = (const float*)d_in[1];  const float* bhf = (const float*)d_in[2];
    const float* Wxf = (const float*)d_in[3];  const float* bxf = (const float*)d_in[4];
    const float* Whi = (const float*)d_in[5];  const float* bhi = (const float*)d_in[6];
    const float* Wxi = (const float*)d_in[7];  const float* bxi = (const float*)d_in[8];
    const float* Whg = (const float*)d_in[9];  const float* bhg = (const float*)d_in[10];
    const float* Wxg = (const float*)d_in[11]; const float* bxg = (const float*)d_in[12];
    const float* Who = (const float*)d_in[13]; const float* bho = (const float*)d_in[14];
    const float* Wxo = (const float*)d_in[15]; const float* bxo = (const float*)d_in[16];

    // ws layout: [0,256KB) tagged h double buffer | [1MB,65MB) XH fp16
    if (ws_size < (size_t)68157440) return;  // need 65 MiB

    char* ws = (char*)d_ws;
    unsigned long long* hws = (unsigned long long*)ws;
    _Float16*           XH  = (_Float16*)(ws + (1 << 20));
    (void)in_sizes; (void)n_in; (void)out_size;

    hipMemsetAsync(d_ws, 0, 262144, stream);
    xcvt<<<16384, 256, 0, stream>>>(X, XH);
    lstm_rec<<<256, 256, 0, stream>>>(Whf, Whi, Whg, Who, Wxf, Wxi, Wxg, Wxo,
                                      bxf, bxi, bxg, bxo, bhf, bhi, bhg, bho,
                                      XH, hws, (float*)d_out);
}